// Round 8
// baseline (1530.407 us; speedup 1.0000x reference)
//
#include <hip/hip_runtime.h>

// RPN head, 5 FPN levels, 3 launches:
//   prep:     conv weights -> fp16 hi/lo [tap][cg][oc][8c]; proj weights ->
//             fp16 hi/lo MFMA A-fragments
//   conv_all: t = relu(conv3x3(feat)+b), implicit GEMM on mfma_32x32x16_f16,
//             A 2-term (hi+lo). Block 128oc x (8x32)px, wave 64oc x 128px
//             (of=2, pf=4 -> 4:1 MFMA:A-load), double-buffered LDS staging.
//             t stored NHWC fp16 [px][256].
//   proj_all: 48x256 projection as mfma_16x16x32_f16, LDS bounce, per-px
//             reparam sample + gumbel softmax + bbox.

#define WT_F   (9*256*256)
#define PA_F   (3*8*64*8)      // 12288 halfs per (hi|lo)
#define TOTAL_PER_B 537138L
#define NTILE  2799            // 64-px proj wave-tiles over all levels

typedef __attribute__((ext_vector_type(8))) _Float16 half8;
typedef __attribute__((ext_vector_type(4))) _Float16 half4;
typedef __attribute__((ext_vector_type(16))) float f32x16;
typedef __attribute__((ext_vector_type(4))) float f32x4;

struct ConvParams {
    const float* feat[5];
    long  toff[5];                    // halfs into tbuf (NHWC per level)
    int   Hs[5], Ws[5], gxs[5], cum[5];
};
struct ProjParams {
    const float* eps[5];
    const float* gum[5];
    long  toff[5], loff[5], hws[5];
    int   tcum[5];
};

__global__ void prep_kernel(const float* __restrict__ conv_w,
                            const float* __restrict__ cls_w,
                            const float* __restrict__ off_w,
                            _Float16* __restrict__ wh,
                            _Float16* __restrict__ wl,
                            _Float16* __restrict__ pAh,
                            _Float16* __restrict__ pAl)
{
    int t = blockIdx.x * 256 + threadIdx.x;
    if (t < 8192) {                       // (oc, cg): 256*32
        int oc = t >> 5, cg = t & 31;
        const float4* s4 = (const float4*)(conv_w + ((long)oc * 256 + cg * 8) * 9);
        float w[72];
        #pragma unroll
        for (int i = 0; i < 18; i++) {
            float4 v = s4[i];
            w[i*4+0] = v.x; w[i*4+1] = v.y; w[i*4+2] = v.z; w[i*4+3] = v.w;
        }
        #pragma unroll
        for (int tap = 0; tap < 9; tap++) {
            half8 hv, lv;
            #pragma unroll
            for (int i = 0; i < 8; i++) {
                float x = w[i * 9 + tap];
                _Float16 h = (_Float16)x;
                hv[i] = h;
                lv[i] = (_Float16)(x - (float)h);
            }
            long o = ((long)(tap * 32 + cg) * 256 + oc) * 8;
            *(half8*)(wh + o) = hv;
            *(half8*)(wl + o) = lv;
        }
    }
    if (t < 1536) {                       // proj A-frags: (mt*8+ks)*64 + lane
        int frag = t >> 6;                // 0..23
        int mt = frag >> 3, ks = frag & 7;
        int ln = t & 63;
        int m = mt * 16 + (ln & 15);
        int kb = ks * 32 + (ln >> 4) * 8;
        half8 hv, lv;
        #pragma unroll
        for (int i = 0; i < 8; i++) {
            int c = kb + i;
            float v = 0.f;
            if (m < 2)       v = cls_w[m * 256 + c];
            else if (m < 47) v = off_w[(m - 2) * 256 + c];
            _Float16 h = (_Float16)v;
            hv[i] = h;
            lv[i] = (_Float16)(v - (float)h);
        }
        *(half8*)(pAh + (long)t * 8) = hv;
        *(half8*)(pAl + (long)t * 8) = lv;
    }
}

// Conv: block = 128 oc x (8 rows x 32 cols). 4 waves: oh=wid>>1 (oc 64-half),
// ph=wid&1 (row 4-half). Wave = 64oc x 128px: of=2 x pf=4 (pf = row).
// Staging tile: 32ch x 10rows x 34cols fp16, [pos][40] layout, double-buffered.
__global__ __launch_bounds__(256, 2) void conv_all_kernel(
    ConvParams P,
    const _Float16* __restrict__ wh,
    const _Float16* __restrict__ wl,
    const float* __restrict__ bias,
    _Float16* __restrict__ tbuf)
{
    int tb = blockIdx.x;
    int l = 0;
    #pragma unroll
    for (int i = 0; i < 5; i++) if (tb >= P.cum[i]) l = i + 1;
    int prev = l ? P.cum[l - 1] : 0;
    int rem = tb - prev;
    const int gx = P.gxs[l];
    const int ty = rem / gx;
    const int tx = rem - ty * gx;
    const int H = P.Hs[l], W = P.Ws[l];
    const long hw = (long)H * W;
    const int b   = blockIdx.z >> 1;
    const int ocb = (blockIdx.z & 1) * 128;
    const float* fb = P.feat[l] + (long)b * 256 * hw;
    _Float16* tl = tbuf + P.toff[l] + (long)b * hw * 256;

    __shared__ __align__(16) _Float16 sB[2][340 * 40]; // [buf][10x34 pos][32c+8pad]

    const int tid  = threadIdx.x;
    const int lane = tid & 63;
    const int wid  = tid >> 6;
    const int x0   = tx * 32;
    const int ty0  = ty * 8;
    const int oh   = wid >> 1;
    const int ph   = wid & 1;
    const int lr32 = lane & 31;
    const int kg   = lane >> 5;

    // staging decomposition (per thread, 6 entries, e = qg*340 + pos)
    int s_qg[6], s_pos[6], s_gr[6], s_gc[6];
    #pragma unroll
    for (int i = 0; i < 6; i++) {
        int e = i * 256 + tid;
        if (e >= 1360) e = 1359;
        int qg = e / 340;
        int pos = e - qg * 340;
        int r = pos / 34, col = pos - r * 34;
        s_qg[i] = qg; s_pos[i] = pos;
        s_gr[i] = ty0 + r - 1; s_gc[i] = x0 + col - 1;
    }
    const bool s_act5 = (5 * 256 + tid) < 1360;

#define STAGE_LOAD(C0N, ST)                                                  \
    {                                                                        \
        _Pragma("unroll")                                                    \
        for (int i = 0; i < 6; i++) {                                        \
            half8 v = {};                                                    \
            if ((i < 5 || s_act5) && s_gr[i] >= 0 && s_gr[i] < H &&          \
                s_gc[i] >= 0 && s_gc[i] < W) {                               \
                const float* p = fb + (long)((C0N) + s_qg[i] * 8) * hw +     \
                                 (long)s_gr[i] * W + s_gc[i];                \
                _Pragma("unroll")                                            \
                for (int k = 0; k < 8; k++) { v[k] = (_Float16)(*p); p += hw; } \
            }                                                                \
            ST[i] = v;                                                       \
        }                                                                    \
    }

#define STAGE_WRITE(DST, ST)                                                 \
    {                                                                        \
        _Pragma("unroll")                                                    \
        for (int i = 0; i < 6; i++)                                          \
            if (i < 5 || s_act5)                                             \
                *(half8*)((DST) + s_pos[i] * 40 + s_qg[i] * 8) = ST[i];      \
    }

    f32x16 acc[2][4] = {};   // [of][pf]

    {
        half8 st0[6];
        STAGE_LOAD(0, st0);
        STAGE_WRITE(sB[0], st0);
    }
    __syncthreads();

    #pragma unroll 1
    for (int c0 = 0; c0 < 256; c0 += 32) {
        const int buf = (c0 >> 5) & 1;
        half8 st[6];
        if (c0 < 224) STAGE_LOAD(c0 + 32, st);

        const _Float16* sb = sB[buf];
        #pragma unroll
        for (int tap = 0; tap < 9; tap++) {
            const int dy = tap / 3;
            const int dx = tap - dy * 3;
            #pragma unroll
            for (int ks = 0; ks < 2; ks++) {
                const int cgt = (c0 >> 3) + ks * 2 + kg;
                const long ao = ((long)(tap * 32 + cgt) * 256 + ocb + oh * 64 + lr32) * 8;
                half8 Ah0 = *(const half8*)(wh + ao);
                half8 Ah1 = *(const half8*)(wh + ao + 256);   // +32 oc
                half8 Al0 = *(const half8*)(wl + ao);
                half8 Al1 = *(const half8*)(wl + ao + 256);

                half8 Bv[4];
                #pragma unroll
                for (int pf = 0; pf < 4; pf++) {
                    const int pos = (ph * 4 + pf + dy) * 34 + lr32 + dx;
                    Bv[pf] = *(const half8*)(sb + pos * 40 + ks * 16 + kg * 8);
                }
                #pragma unroll
                for (int pf = 0; pf < 4; pf++)
                    acc[0][pf] = __builtin_amdgcn_mfma_f32_32x32x16_f16(Ah0, Bv[pf], acc[0][pf], 0, 0, 0);
                #pragma unroll
                for (int pf = 0; pf < 4; pf++)
                    acc[1][pf] = __builtin_amdgcn_mfma_f32_32x32x16_f16(Ah1, Bv[pf], acc[1][pf], 0, 0, 0);
                #pragma unroll
                for (int pf = 0; pf < 4; pf++)
                    acc[0][pf] = __builtin_amdgcn_mfma_f32_32x32x16_f16(Al0, Bv[pf], acc[0][pf], 0, 0, 0);
                #pragma unroll
                for (int pf = 0; pf < 4; pf++)
                    acc[1][pf] = __builtin_amdgcn_mfma_f32_32x32x16_f16(Al1, Bv[pf], acc[1][pf], 0, 0, 0);
            }
        }

        if (c0 < 224) STAGE_WRITE(sB[buf ^ 1], st);
        __syncthreads();
    }

    // epilogue: bias+relu, NHWC fp16, packed 4-oc (8 B) stores.
    // C/D 32x32: col(px)=lane&31, row(oc)=(rg&3)+8*(rg>>2)+4*kg
    const int x = x0 + lr32;
    if (x < W) {
        #pragma unroll
        for (int pf = 0; pf < 4; pf++) {
            const int row = ty0 + ph * 4 + pf;
            if (row < H) {
                long pb = ((long)row * W + x) * 256;
                #pragma unroll
                for (int of = 0; of < 2; of++) {
                    #pragma unroll
                    for (int q = 0; q < 4; q++) {
                        const int ob = ocb + oh * 64 + of * 32 + kg * 4 + 8 * q;
                        float4 b4 = *(const float4*)(bias + ob);
                        half4 hv;
                        hv[0] = (_Float16)fmaxf(acc[of][pf][q * 4 + 0] + b4.x, 0.f);
                        hv[1] = (_Float16)fmaxf(acc[of][pf][q * 4 + 1] + b4.y, 0.f);
                        hv[2] = (_Float16)fmaxf(acc[of][pf][q * 4 + 2] + b4.z, 0.f);
                        hv[3] = (_Float16)fmaxf(acc[of][pf][q * 4 + 3] + b4.w, 0.f);
                        *(half4*)(tl + pb + ob) = hv;
                    }
                }
            }
        }
    }
#undef STAGE_LOAD
#undef STAGE_WRITE
}

// Proj: each wave owns one 64-px tile. MFMA 48x256 x px, LDS bounce, epilogue.
__global__ __launch_bounds__(256, 2) void proj_all_kernel(
    ProjParams P,
    const _Float16* __restrict__ tbuf,
    const _Float16* __restrict__ pAh,
    const _Float16* __restrict__ pAl,
    const float* __restrict__ cls_b,
    const float* __restrict__ off_b,
    float* __restrict__ out)
{
    __shared__ __align__(16) float sOut[4][64 * 52];
    const int tid  = threadIdx.x;
    const int lane = tid & 63;
    const int wid  = tid >> 6;

    int tile = blockIdx.x * 4 + wid;
    const bool tvalid = tile < NTILE;
    if (!tvalid) tile = NTILE - 1;
    int l = 0;
    #pragma unroll
    for (int i = 0; i < 5; i++) if (tile >= P.tcum[i]) l = i + 1;
    const int tprev = l ? P.tcum[l - 1] : 0;
    const long hw = P.hws[l];
    const long npx2 = 2 * hw;
    const long px0 = (long)(tile - tprev) * 64;
    const _Float16* tl = tbuf + P.toff[l];

    const int m16 = lane & 15;
    const int kq  = lane >> 4;

    f32x4 acc[3][4] = {};
    #pragma unroll
    for (int ks = 0; ks < 8; ks++) {
        half8 Ah[3], Al[3];
        #pragma unroll
        for (int mt = 0; mt < 3; mt++) {
            const long ao = (long)((mt * 8 + ks) * 64 + lane) * 8;
            Ah[mt] = *(const half8*)(pAh + ao);
            Al[mt] = *(const half8*)(pAl + ao);
        }
        #pragma unroll
        for (int nf = 0; nf < 4; nf++) {
            long px2 = px0 + nf * 16 + m16;
            if (px2 >= npx2) px2 = npx2 - 1;
            half8 Bv = *(const half8*)(tl + px2 * 256 + ks * 32 + kq * 8);
            #pragma unroll
            for (int mt = 0; mt < 3; mt++) {
                acc[mt][nf] = __builtin_amdgcn_mfma_f32_16x16x32_f16(Ah[mt], Bv, acc[mt][nf], 0, 0, 0);
                acc[mt][nf] = __builtin_amdgcn_mfma_f32_16x16x32_f16(Al[mt], Bv, acc[mt][nf], 0, 0, 0);
            }
        }
    }

    // bounce: [px-in-tile][52] fp32, conflict-free stride
    float* so = sOut[wid];
    #pragma unroll
    for (int nf = 0; nf < 4; nf++)
        #pragma unroll
        for (int mt = 0; mt < 3; mt++)
            *(f32x4*)(so + (nf * 16 + m16) * 52 + mt * 16 + kq * 4) = acc[mt][nf];
    __syncthreads();

    float v[48];
    #pragma unroll
    for (int j = 0; j < 12; j++) {
        f32x4 t4 = *(const f32x4*)(so + lane * 52 + j * 4);
        v[j*4+0] = t4[0]; v[j*4+1] = t4[1]; v[j*4+2] = t4[2]; v[j*4+3] = t4[3];
    }

    long px2 = px0 + lane;
    const bool pvalid = tvalid && (px2 < npx2);
    if (px2 >= npx2) px2 = npx2 - 1;
    const int b = px2 >= hw;
    const long pix = px2 - (b ? hw : 0);

    const float* eb = P.eps[l] + (long)b * 20 * hw + pix;
    const float* gb = P.gum[l] + (long)b * 5 * hw + pix;

    float wlog[5];
    float m = -1e30f;
    #pragma unroll
    for (int k = 0; k < 5; k++) {
        float u = gb[(long)k * hw];
        float g = -logf(-logf(u + 1e-10f) + 1e-10f);
        wlog[k] = (g + v[42 + k] + off_b[40 + k]) * 10.0f;
        m = fmaxf(m, wlog[k]);
    }
    float s = 0.f, cw[5];
    #pragma unroll
    for (int k = 0; k < 5; k++) { cw[k] = expf(wlog[k] - m); s += cw[k]; }
    float inv = 1.0f / s;

    float bbox[4] = {0.f, 0.f, 0.f, 0.f};
    #pragma unroll
    for (int k = 0; k < 5; k++) {
        float cwk = cw[k] * inv;
        #pragma unroll
        for (int j = 0; j < 4; j++) {
            int kj = k * 4 + j;
            float mean = v[2 + kj]  + off_b[kj];
            float lstd = v[22 + kj] + off_b[20 + kj];
            float sv = fmaf(expf(lstd), eb[(long)kj * hw], mean);
            bbox[j] = fmaf(cwk, sv, bbox[j]);
        }
    }

    if (pvalid) {
        float* ob = out + (long)b * TOTAL_PER_B + P.loff[l];
        float2 c2; c2.x = v[0] + cls_b[0]; c2.y = v[1] + cls_b[1];
        *(float2*)(ob + pix * 2) = c2;
        float* o2 = ob + hw * 2 + pix * 4;
        float2 b01; b01.x = bbox[0]; b01.y = bbox[1];
        float2 b23; b23.x = bbox[2]; b23.y = bbox[3];
        *(float2*)o2 = b01;
        *(float2*)(o2 + 2) = b23;
    }
}

extern "C" void kernel_launch(void* const* d_in, const int* in_sizes, int n_in,
                              void* d_out, int out_size, void* d_ws, size_t ws_size,
                              hipStream_t stream)
{
    static const int LH[5] = {200, 100, 50, 25, 13};
    static const int LW[5] = {336, 168, 84, 42, 21};

    const float* conv_w = (const float*)d_in[15];
    const float* conv_b = (const float*)d_in[16];
    const float* cls_w  = (const float*)d_in[17];
    const float* cls_b  = (const float*)d_in[18];
    const float* off_w  = (const float*)d_in[19];
    const float* off_b  = (const float*)d_in[20];

    _Float16* wh  = (_Float16*)d_ws;
    _Float16* wl  = wh + WT_F;
    _Float16* pAh = wl + WT_F;
    _Float16* pAl = pAh + PA_F;
    _Float16* tbuf = pAl + PA_F;

    ConvParams cp;
    ProjParams pp;
    long toff = 0, loff = 0;
    int cum = 0, tcum = 0;
    for (int l = 0; l < 5; l++) {
        int H = LH[l], W = LW[l];
        long hw = (long)H * W;
        cp.feat[l] = (const float*)d_in[3 * l];
        pp.eps[l]  = (const float*)d_in[3 * l + 1];
        pp.gum[l]  = (const float*)d_in[3 * l + 2];
        cp.toff[l] = toff; pp.toff[l] = toff;
        cp.Hs[l] = H; cp.Ws[l] = W;
        pp.hws[l] = hw;
        int gx = (W + 31) / 32, gy = (H + 7) / 8;
        cp.gxs[l] = gx;
        cum += gx * gy;
        cp.cum[l] = cum;
        pp.loff[l] = loff;
        tcum += (int)((2 * hw + 63) / 64);
        pp.tcum[l] = tcum;
        toff += 2L * hw * 256;
        loff += 6L * hw;
    }

    prep_kernel<<<32, 256, 0, stream>>>(conv_w, cls_w, off_w, wh, wl, pAh, pAl);

    conv_all_kernel<<<dim3((unsigned)cum, 1, 4), 256, 0, stream>>>(
        cp, wh, wl, conv_b, tbuf);

    proj_all_kernel<<<dim3((unsigned)((NTILE + 3) / 4)), 256, 0, stream>>>(
        pp, tbuf, pAh, pAl, cls_b, off_b, (float*)d_out);
}

// Round 9
// 1270.327 us; speedup vs baseline: 1.2047x; 1.2047x over previous
//
#include <hip/hip_runtime.h>

// RPN head, 5 FPN levels, 3 launches:
//   prep:     conv weights -> fp16 hi/lo [tap][cg][oc][8c]; proj weights ->
//             fp16 hi/lo MFMA A-fragments
//   conv_all: t = relu(conv3x3(feat)+b), implicit GEMM on mfma_32x32x16_f16,
//             A 2-term (hi+lo). Round-6 footprint: block 256oc x (8x16)px, z=b.
//             NEW: wave = 64oc x 128px (of=2, pf=4 -> 4:1 MFMA:A-load) and
//             double-buffered LDS staging (load-early / ds_write-late).
//             t stored NHWC fp16 [px][256].
//   proj_all: 48x256 projection as mfma_16x16x32_f16, LDS bounce, per-px
//             reparam sample + gumbel softmax + bbox.

#define WT_F   (9*256*256)
#define PA_F   (3*8*64*8)      // 12288 halfs per (hi|lo)
#define TOTAL_PER_B 537138L
#define NTILE  2799            // 64-px proj wave-tiles over all levels

typedef __attribute__((ext_vector_type(8))) _Float16 half8;
typedef __attribute__((ext_vector_type(4))) _Float16 half4;
typedef __attribute__((ext_vector_type(16))) float f32x16;
typedef __attribute__((ext_vector_type(4))) float f32x4;

struct ConvParams {
    const float* feat[5];
    long  toff[5];                    // halfs into tbuf (NHWC per level)
    int   Hs[5], Ws[5], gxs[5], cum[5];
};
struct ProjParams {
    const float* eps[5];
    const float* gum[5];
    long  toff[5], loff[5], hws[5];
    int   tcum[5];
};

__global__ void prep_kernel(const float* __restrict__ conv_w,
                            const float* __restrict__ cls_w,
                            const float* __restrict__ off_w,
                            _Float16* __restrict__ wh,
                            _Float16* __restrict__ wl,
                            _Float16* __restrict__ pAh,
                            _Float16* __restrict__ pAl)
{
    int t = blockIdx.x * 256 + threadIdx.x;
    if (t < 8192) {                       // (oc, cg): 256*32
        int oc = t >> 5, cg = t & 31;
        const float4* s4 = (const float4*)(conv_w + ((long)oc * 256 + cg * 8) * 9);
        float w[72];
        #pragma unroll
        for (int i = 0; i < 18; i++) {
            float4 v = s4[i];
            w[i*4+0] = v.x; w[i*4+1] = v.y; w[i*4+2] = v.z; w[i*4+3] = v.w;
        }
        #pragma unroll
        for (int tap = 0; tap < 9; tap++) {
            half8 hv, lv;
            #pragma unroll
            for (int i = 0; i < 8; i++) {
                float x = w[i * 9 + tap];
                _Float16 h = (_Float16)x;
                hv[i] = h;
                lv[i] = (_Float16)(x - (float)h);
            }
            long o = ((long)(tap * 32 + cg) * 256 + oc) * 8;
            *(half8*)(wh + o) = hv;
            *(half8*)(wl + o) = lv;
        }
    }
    if (t < 1536) {                       // proj A-frags: (mt*8+ks)*64 + lane
        int frag = t >> 6;                // 0..23
        int mt = frag >> 3, ks = frag & 7;
        int ln = t & 63;
        int m = mt * 16 + (ln & 15);
        int kb = ks * 32 + (ln >> 4) * 8;
        half8 hv, lv;
        #pragma unroll
        for (int i = 0; i < 8; i++) {
            int c = kb + i;
            float v = 0.f;
            if (m < 2)       v = cls_w[m * 256 + c];
            else if (m < 47) v = off_w[(m - 2) * 256 + c];
            _Float16 h = (_Float16)v;
            hv[i] = h;
            lv[i] = (_Float16)(v - (float)h);
        }
        *(half8*)(pAh + (long)t * 8) = hv;
        *(half8*)(pAl + (long)t * 8) = lv;
    }
}

// Conv: block = 256 oc x (8 rows x 16 cols) px, z = batch. 4 waves = 4 oc
// quarters; each wave = 64oc x all 128px: of=2 x pf=4 (pf = row-pair).
// Staging: 32ch x 10x18 halo, [pos][40] fp16, double-buffered (28.8 KB).
__global__ __launch_bounds__(256, 2) void conv_all_kernel(
    ConvParams P,
    const _Float16* __restrict__ wh,
    const _Float16* __restrict__ wl,
    const float* __restrict__ bias,
    _Float16* __restrict__ tbuf)
{
    int tb = blockIdx.x;
    int l = 0;
    #pragma unroll
    for (int i = 0; i < 5; i++) if (tb >= P.cum[i]) l = i + 1;
    int prev = l ? P.cum[l - 1] : 0;
    int rem = tb - prev;
    const int gx = P.gxs[l];
    const int ty = rem / gx;
    const int tx = rem - ty * gx;
    const int H = P.Hs[l], W = P.Ws[l];
    const long hw = (long)H * W;
    const int b = blockIdx.z;
    const float* fb = P.feat[l] + (long)b * 256 * hw;
    _Float16* tl = tbuf + P.toff[l] + (long)b * hw * 256;

    __shared__ __align__(16) _Float16 sB[2][180 * 40]; // [buf][10x18 pos][32c+8pad]

    const int tid  = threadIdx.x;
    const int lane = tid & 63;
    const int wid  = tid >> 6;        // oc quarter
    const int x0   = tx * 16;
    const int ty0  = ty * 8;
    const int lr32 = lane & 31;
    const int kg   = lane >> 5;
    const int nrow = lr32 >> 4;
    const int ncol = lane & 15;

    // staging decomposition (3 entries/thread, e = qg*180 + pos, 720 total)
    int s_qg[3], s_pos[3], s_gr[3], s_gc[3];
    bool s_act[3];
    #pragma unroll
    for (int i = 0; i < 3; i++) {
        int e = i * 256 + tid;
        s_act[i] = e < 720;
        if (e >= 720) e = 719;
        int qg = e / 180;
        int pos = e - qg * 180;
        int r = pos / 18, col = pos - r * 18;
        s_qg[i] = qg; s_pos[i] = pos;
        s_gr[i] = ty0 + r - 1; s_gc[i] = x0 + col - 1;
    }

#define STAGE_LOAD(C0N, ST)                                                  \
    {                                                                        \
        _Pragma("unroll")                                                    \
        for (int i = 0; i < 3; i++) {                                        \
            half8 v = {};                                                    \
            if (s_act[i] && s_gr[i] >= 0 && s_gr[i] < H &&                   \
                s_gc[i] >= 0 && s_gc[i] < W) {                               \
                const float* p = fb + (long)((C0N) + s_qg[i] * 8) * hw +     \
                                 (long)s_gr[i] * W + s_gc[i];                \
                _Pragma("unroll")                                            \
                for (int k = 0; k < 8; k++) { v[k] = (_Float16)(*p); p += hw; } \
            }                                                                \
            ST[i] = v;                                                       \
        }                                                                    \
    }

#define STAGE_WRITE(DST, ST)                                                 \
    {                                                                        \
        _Pragma("unroll")                                                    \
        for (int i = 0; i < 3; i++)                                          \
            if (s_act[i])                                                    \
                *(half8*)((DST) + s_pos[i] * 40 + s_qg[i] * 8) = ST[i];      \
    }

    f32x16 acc[2][4] = {};   // [of][pf]

    {
        half8 st0[3];
        STAGE_LOAD(0, st0);
        STAGE_WRITE(sB[0], st0);
    }
    __syncthreads();

    #pragma unroll 1
    for (int c0 = 0; c0 < 256; c0 += 32) {
        const int buf = (c0 >> 5) & 1;
        half8 st[3];
        if (c0 < 224) STAGE_LOAD(c0 + 32, st);   // issue early: hide under MFMAs

        const _Float16* sb = sB[buf];
        #pragma unroll
        for (int tap = 0; tap < 9; tap++) {
            const int dy = tap / 3;
            const int dx = tap - dy * 3;
            #pragma unroll
            for (int ks = 0; ks < 2; ks++) {
                const int cgt = (c0 >> 3) + ks * 2 + kg;
                const long ao = ((long)(tap * 32 + cgt) * 256 + wid * 64 + lr32) * 8;
                half8 Ah0 = *(const half8*)(wh + ao);
                half8 Ah1 = *(const half8*)(wh + ao + 256);   // +32 oc
                half8 Al0 = *(const half8*)(wl + ao);
                half8 Al1 = *(const half8*)(wl + ao + 256);

                half8 Bv[4];
                #pragma unroll
                for (int pf = 0; pf < 4; pf++) {
                    const int pos = (pf * 2 + nrow + dy) * 18 + ncol + dx;
                    Bv[pf] = *(const half8*)(sb + pos * 40 + ks * 16 + kg * 8);
                }
                #pragma unroll
                for (int pf = 0; pf < 4; pf++)
                    acc[0][pf] = __builtin_amdgcn_mfma_f32_32x32x16_f16(Ah0, Bv[pf], acc[0][pf], 0, 0, 0);
                #pragma unroll
                for (int pf = 0; pf < 4; pf++)
                    acc[1][pf] = __builtin_amdgcn_mfma_f32_32x32x16_f16(Ah1, Bv[pf], acc[1][pf], 0, 0, 0);
                #pragma unroll
                for (int pf = 0; pf < 4; pf++)
                    acc[0][pf] = __builtin_amdgcn_mfma_f32_32x32x16_f16(Al0, Bv[pf], acc[0][pf], 0, 0, 0);
                #pragma unroll
                for (int pf = 0; pf < 4; pf++)
                    acc[1][pf] = __builtin_amdgcn_mfma_f32_32x32x16_f16(Al1, Bv[pf], acc[1][pf], 0, 0, 0);
            }
        }

        if (c0 < 224) STAGE_WRITE(sB[buf ^ 1], st);  // write late, after compute
        __syncthreads();
    }

    // epilogue: bias+relu, NHWC fp16, packed 4-oc (8 B) stores.
    // C/D 32x32: col(px)=lane&31 (= nrow*16+ncol), row(oc)=(rg&3)+8*(rg>>2)+4*kg
    const int x = x0 + ncol;
    if (x < W) {
        #pragma unroll
        for (int pf = 0; pf < 4; pf++) {
            const int row = ty0 + pf * 2 + nrow;
            if (row < H) {
                long pb = ((long)row * W + x) * 256;
                #pragma unroll
                for (int of = 0; of < 2; of++) {
                    #pragma unroll
                    for (int q = 0; q < 4; q++) {
                        const int ob = wid * 64 + of * 32 + kg * 4 + 8 * q;
                        float4 b4 = *(const float4*)(bias + ob);
                        half4 hv;
                        hv[0] = (_Float16)fmaxf(acc[of][pf][q * 4 + 0] + b4.x, 0.f);
                        hv[1] = (_Float16)fmaxf(acc[of][pf][q * 4 + 1] + b4.y, 0.f);
                        hv[2] = (_Float16)fmaxf(acc[of][pf][q * 4 + 2] + b4.z, 0.f);
                        hv[3] = (_Float16)fmaxf(acc[of][pf][q * 4 + 3] + b4.w, 0.f);
                        *(half4*)(tl + pb + ob) = hv;
                    }
                }
            }
        }
    }
#undef STAGE_LOAD
#undef STAGE_WRITE
}

// Proj: each wave owns one 64-px tile. MFMA 48x256 x px, LDS bounce, epilogue.
__global__ __launch_bounds__(256, 2) void proj_all_kernel(
    ProjParams P,
    const _Float16* __restrict__ tbuf,
    const _Float16* __restrict__ pAh,
    const _Float16* __restrict__ pAl,
    const float* __restrict__ cls_b,
    const float* __restrict__ off_b,
    float* __restrict__ out)
{
    __shared__ __align__(16) float sOut[4][64 * 52];
    const int tid  = threadIdx.x;
    const int lane = tid & 63;
    const int wid  = tid >> 6;

    int tile = blockIdx.x * 4 + wid;
    const bool tvalid = tile < NTILE;
    if (!tvalid) tile = NTILE - 1;
    int l = 0;
    #pragma unroll
    for (int i = 0; i < 5; i++) if (tile >= P.tcum[i]) l = i + 1;
    const int tprev = l ? P.tcum[l - 1] : 0;
    const long hw = P.hws[l];
    const long npx2 = 2 * hw;
    const long px0 = (long)(tile - tprev) * 64;
    const _Float16* tl = tbuf + P.toff[l];

    const int m16 = lane & 15;
    const int kq  = lane >> 4;

    f32x4 acc[3][4] = {};
    #pragma unroll
    for (int ks = 0; ks < 8; ks++) {
        half8 Ah[3], Al[3];
        #pragma unroll
        for (int mt = 0; mt < 3; mt++) {
            const long ao = (long)((mt * 8 + ks) * 64 + lane) * 8;
            Ah[mt] = *(const half8*)(pAh + ao);
            Al[mt] = *(const half8*)(pAl + ao);
        }
        #pragma unroll
        for (int nf = 0; nf < 4; nf++) {
            long px2 = px0 + nf * 16 + m16;
            if (px2 >= npx2) px2 = npx2 - 1;
            half8 Bv = *(const half8*)(tl + px2 * 256 + ks * 32 + kq * 8);
            #pragma unroll
            for (int mt = 0; mt < 3; mt++) {
                acc[mt][nf] = __builtin_amdgcn_mfma_f32_16x16x32_f16(Ah[mt], Bv, acc[mt][nf], 0, 0, 0);
                acc[mt][nf] = __builtin_amdgcn_mfma_f32_16x16x32_f16(Al[mt], Bv, acc[mt][nf], 0, 0, 0);
            }
        }
    }

    // bounce: [px-in-tile][52] fp32, conflict-free stride
    float* so = sOut[wid];
    #pragma unroll
    for (int nf = 0; nf < 4; nf++)
        #pragma unroll
        for (int mt = 0; mt < 3; mt++)
            *(f32x4*)(so + (nf * 16 + m16) * 52 + mt * 16 + kq * 4) = acc[mt][nf];
    __syncthreads();

    float v[48];
    #pragma unroll
    for (int j = 0; j < 12; j++) {
        f32x4 t4 = *(const f32x4*)(so + lane * 52 + j * 4);
        v[j*4+0] = t4[0]; v[j*4+1] = t4[1]; v[j*4+2] = t4[2]; v[j*4+3] = t4[3];
    }

    long px2 = px0 + lane;
    const bool pvalid = tvalid && (px2 < npx2);
    if (px2 >= npx2) px2 = npx2 - 1;
    const int b = px2 >= hw;
    const long pix = px2 - (b ? hw : 0);

    const float* eb = P.eps[l] + (long)b * 20 * hw + pix;
    const float* gb = P.gum[l] + (long)b * 5 * hw + pix;

    float wlog[5];
    float m = -1e30f;
    #pragma unroll
    for (int k = 0; k < 5; k++) {
        float u = gb[(long)k * hw];
        float g = -logf(-logf(u + 1e-10f) + 1e-10f);
        wlog[k] = (g + v[42 + k] + off_b[40 + k]) * 10.0f;
        m = fmaxf(m, wlog[k]);
    }
    float s = 0.f, cw[5];
    #pragma unroll
    for (int k = 0; k < 5; k++) { cw[k] = expf(wlog[k] - m); s += cw[k]; }
    float inv = 1.0f / s;

    float bbox[4] = {0.f, 0.f, 0.f, 0.f};
    #pragma unroll
    for (int k = 0; k < 5; k++) {
        float cwk = cw[k] * inv;
        #pragma unroll
        for (int j = 0; j < 4; j++) {
            int kj = k * 4 + j;
            float mean = v[2 + kj]  + off_b[kj];
            float lstd = v[22 + kj] + off_b[20 + kj];
            float sv = fmaf(expf(lstd), eb[(long)kj * hw], mean);
            bbox[j] = fmaf(cwk, sv, bbox[j]);
        }
    }

    if (pvalid) {
        float* ob = out + (long)b * TOTAL_PER_B + P.loff[l];
        float2 c2; c2.x = v[0] + cls_b[0]; c2.y = v[1] + cls_b[1];
        *(float2*)(ob + pix * 2) = c2;
        float* o2 = ob + hw * 2 + pix * 4;
        float2 b01; b01.x = bbox[0]; b01.y = bbox[1];
        float2 b23; b23.x = bbox[2]; b23.y = bbox[3];
        *(float2*)o2 = b01;
        *(float2*)(o2 + 2) = b23;
    }
}

extern "C" void kernel_launch(void* const* d_in, const int* in_sizes, int n_in,
                              void* d_out, int out_size, void* d_ws, size_t ws_size,
                              hipStream_t stream)
{
    static const int LH[5] = {200, 100, 50, 25, 13};
    static const int LW[5] = {336, 168, 84, 42, 21};

    const float* conv_w = (const float*)d_in[15];
    const float* conv_b = (const float*)d_in[16];
    const float* cls_w  = (const float*)d_in[17];
    const float* cls_b  = (const float*)d_in[18];
    const float* off_w  = (const float*)d_in[19];
    const float* off_b  = (const float*)d_in[20];

    _Float16* wh  = (_Float16*)d_ws;
    _Float16* wl  = wh + WT_F;
    _Float16* pAh = wl + WT_F;
    _Float16* pAl = pAh + PA_F;
    _Float16* tbuf = pAl + PA_F;

    ConvParams cp;
    ProjParams pp;
    long toff = 0, loff = 0;
    int cum = 0, tcum = 0;
    for (int l = 0; l < 5; l++) {
        int H = LH[l], W = LW[l];
        long hw = (long)H * W;
        cp.feat[l] = (const float*)d_in[3 * l];
        pp.eps[l]  = (const float*)d_in[3 * l + 1];
        pp.gum[l]  = (const float*)d_in[3 * l + 2];
        cp.toff[l] = toff; pp.toff[l] = toff;
        cp.Hs[l] = H; cp.Ws[l] = W;
        pp.hws[l] = hw;
        int gx = (W + 15) / 16, gy = (H + 7) / 8;
        cp.gxs[l] = gx;
        cum += gx * gy;
        cp.cum[l] = cum;
        pp.loff[l] = loff;
        tcum += (int)((2 * hw + 63) / 64);
        pp.tcum[l] = tcum;
        toff += 2L * hw * 256;
        loff += 6L * hw;
    }

    prep_kernel<<<32, 256, 0, stream>>>(conv_w, cls_w, off_w, wh, wl, pAh, pAl);

    conv_all_kernel<<<dim3((unsigned)cum, 1, 2), 256, 0, stream>>>(
        cp, wh, wl, conv_b, tbuf);

    proj_all_kernel<<<dim3((unsigned)((NTILE + 3) / 4)), 256, 0, stream>>>(
        pp, tbuf, pAh, pAl, cls_b, off_b, (float*)d_out);
}

// Round 10
// 878.983 us; speedup vs baseline: 1.7411x; 1.4452x over previous
//
#include <hip/hip_runtime.h>

// RPN head, 5 FPN levels, 3 launches:
//   prep:     conv weights -> fp16 hi/lo [tap][cg][oc][8c]; proj weights ->
//             fp16 hi/lo MFMA A-fragments
//   conv_all: t = relu(conv3x3(feat)+b), implicit GEMM on mfma_32x32x16_f16,
//             A 2-term (hi+lo). Round-6 structure (single-buffer LDS, tight
//             staging, 2 barriers/iter). Wave mapping: 4 waves = 4 oc-quarters
//             (64oc), each computes all 128 px (of=2 x pf=4) -> 4:1 MFMA:A-load,
//             no cross-wave weight duplication, no long-lived staging regs.
//             t stored NHWC fp16 [px][256].
//   proj_all: 48x256 projection as mfma_16x16x32_f16, LDS bounce, per-px
//             reparam sample + gumbel softmax + bbox.

#define WT_F   (9*256*256)
#define PA_F   (3*8*64*8)      // 12288 halfs per (hi|lo)
#define TOTAL_PER_B 537138L
#define NTILE  2799            // 64-px proj wave-tiles over all levels

typedef __attribute__((ext_vector_type(8))) _Float16 half8;
typedef __attribute__((ext_vector_type(4))) _Float16 half4;
typedef __attribute__((ext_vector_type(16))) float f32x16;
typedef __attribute__((ext_vector_type(4))) float f32x4;

struct ConvParams {
    const float* feat[5];
    long  toff[5];                    // halfs into tbuf (NHWC per level)
    int   Hs[5], Ws[5], gxs[5], cum[5];
};
struct ProjParams {
    const float* eps[5];
    const float* gum[5];
    long  toff[5], loff[5], hws[5];
    int   tcum[5];
};

__global__ void prep_kernel(const float* __restrict__ conv_w,
                            const float* __restrict__ cls_w,
                            const float* __restrict__ off_w,
                            _Float16* __restrict__ wh,
                            _Float16* __restrict__ wl,
                            _Float16* __restrict__ pAh,
                            _Float16* __restrict__ pAl)
{
    int t = blockIdx.x * 256 + threadIdx.x;
    if (t < 8192) {                       // (oc, cg): 256*32
        int oc = t >> 5, cg = t & 31;
        const float4* s4 = (const float4*)(conv_w + ((long)oc * 256 + cg * 8) * 9);
        float w[72];
        #pragma unroll
        for (int i = 0; i < 18; i++) {
            float4 v = s4[i];
            w[i*4+0] = v.x; w[i*4+1] = v.y; w[i*4+2] = v.z; w[i*4+3] = v.w;
        }
        #pragma unroll
        for (int tap = 0; tap < 9; tap++) {
            half8 hv, lv;
            #pragma unroll
            for (int i = 0; i < 8; i++) {
                float x = w[i * 9 + tap];
                _Float16 h = (_Float16)x;
                hv[i] = h;
                lv[i] = (_Float16)(x - (float)h);
            }
            long o = ((long)(tap * 32 + cg) * 256 + oc) * 8;
            *(half8*)(wh + o) = hv;
            *(half8*)(wl + o) = lv;
        }
    }
    if (t < 1536) {                       // proj A-frags: (mt*8+ks)*64 + lane
        int frag = t >> 6;                // 0..23
        int mt = frag >> 3, ks = frag & 7;
        int ln = t & 63;
        int m = mt * 16 + (ln & 15);
        int kb = ks * 32 + (ln >> 4) * 8;
        half8 hv, lv;
        #pragma unroll
        for (int i = 0; i < 8; i++) {
            int c = kb + i;
            float v = 0.f;
            if (m < 2)       v = cls_w[m * 256 + c];
            else if (m < 47) v = off_w[(m - 2) * 256 + c];
            _Float16 h = (_Float16)v;
            hv[i] = h;
            lv[i] = (_Float16)(v - (float)h);
        }
        *(half8*)(pAh + (long)t * 8) = hv;
        *(half8*)(pAl + (long)t * 8) = lv;
    }
}

// Conv: block = 256 oc x (8 rows x 16 cols) px, z = batch. 4 waves = 4 oc
// quarters (64 oc); each wave computes all 128 px: of=2 x pf=4 (pf = row-pair).
// Staging: 32ch x 10x18 halo, [pos][40] fp16, SINGLE buffer, tight
// load->convert->write with two barriers per c0 iter (round-6 structure).
__global__ __launch_bounds__(256, 2) void conv_all_kernel(
    ConvParams P,
    const _Float16* __restrict__ wh,
    const _Float16* __restrict__ wl,
    const float* __restrict__ bias,
    _Float16* __restrict__ tbuf)
{
    int tb = blockIdx.x;
    int l = 0;
    #pragma unroll
    for (int i = 0; i < 5; i++) if (tb >= P.cum[i]) l = i + 1;
    int prev = l ? P.cum[l - 1] : 0;
    int rem = tb - prev;
    const int gx = P.gxs[l];
    const int ty = rem / gx;
    const int tx = rem - ty * gx;
    const int H = P.Hs[l], W = P.Ws[l];
    const long hw = (long)H * W;
    const int b = blockIdx.z;
    const float* fb = P.feat[l] + (long)b * 256 * hw;
    _Float16* tl = tbuf + P.toff[l] + (long)b * hw * 256;

    __shared__ __align__(16) _Float16 sB[180 * 40];  // [10x18 pos][32c + 8 pad]

    const int tid  = threadIdx.x;
    const int lane = tid & 63;
    const int wid  = tid >> 6;        // oc quarter
    const int x0   = tx * 16;
    const int ty0  = ty * 8;
    const int lr32 = lane & 31;
    const int kg   = lane >> 5;
    const int nrow = lr32 >> 4;
    const int ncol = lane & 15;

    f32x16 acc[2][4] = {};   // [of][pf]

    for (int c0 = 0; c0 < 256; c0 += 32) {
        __syncthreads();
        // stage 32 ch x 10x18 halo tile: fp32 loads -> fp16 pack -> one b128 write
        for (int e = tid; e < 720; e += 256) {
            int qg  = e / 180;            // channel octet 0..3
            int pos = e - qg * 180;
            int r   = pos / 18;
            int col = pos - r * 18;
            int gr = ty0 + r - 1;
            int gc = x0 + col - 1;
            half8 v = {};
            if (gr >= 0 && gr < H && gc >= 0 && gc < W) {
                const float* p = fb + (long)(c0 + qg * 8) * hw + (long)gr * W + gc;
                #pragma unroll
                for (int i = 0; i < 8; i++) { v[i] = (_Float16)(*p); p += hw; }
            }
            *(half8*)(sB + pos * 40 + qg * 8) = v;
        }
        __syncthreads();

        #pragma unroll
        for (int tap = 0; tap < 9; tap++) {
            const int dy = tap / 3;
            const int dx = tap - dy * 3;
            #pragma unroll
            for (int ks = 0; ks < 2; ks++) {
                const int cgt = (c0 >> 3) + ks * 2 + kg;
                const long ao = ((long)(tap * 32 + cgt) * 256 + wid * 64 + lr32) * 8;
                half8 Ah0 = *(const half8*)(wh + ao);
                half8 Ah1 = *(const half8*)(wh + ao + 256);   // +32 oc
                half8 Al0 = *(const half8*)(wl + ao);
                half8 Al1 = *(const half8*)(wl + ao + 256);

                half8 Bv[4];
                #pragma unroll
                for (int pf = 0; pf < 4; pf++) {
                    const int pos = (pf * 2 + nrow + dy) * 18 + ncol + dx;
                    Bv[pf] = *(const half8*)(sB + pos * 40 + ks * 16 + kg * 8);
                }
                #pragma unroll
                for (int pf = 0; pf < 4; pf++)
                    acc[0][pf] = __builtin_amdgcn_mfma_f32_32x32x16_f16(Ah0, Bv[pf], acc[0][pf], 0, 0, 0);
                #pragma unroll
                for (int pf = 0; pf < 4; pf++)
                    acc[1][pf] = __builtin_amdgcn_mfma_f32_32x32x16_f16(Ah1, Bv[pf], acc[1][pf], 0, 0, 0);
                #pragma unroll
                for (int pf = 0; pf < 4; pf++)
                    acc[0][pf] = __builtin_amdgcn_mfma_f32_32x32x16_f16(Al0, Bv[pf], acc[0][pf], 0, 0, 0);
                #pragma unroll
                for (int pf = 0; pf < 4; pf++)
                    acc[1][pf] = __builtin_amdgcn_mfma_f32_32x32x16_f16(Al1, Bv[pf], acc[1][pf], 0, 0, 0);
            }
        }
    }

    // epilogue: bias+relu, NHWC fp16, packed 4-oc (8 B) stores.
    // C/D 32x32: col(px)=lane&31 (= nrow*16+ncol), row(oc)=(rg&3)+8*(rg>>2)+4*kg
    const int x = x0 + ncol;
    if (x < W) {
        #pragma unroll
        for (int pf = 0; pf < 4; pf++) {
            const int row = ty0 + pf * 2 + nrow;
            if (row < H) {
                long pb = ((long)row * W + x) * 256;
                #pragma unroll
                for (int of = 0; of < 2; of++) {
                    #pragma unroll
                    for (int q = 0; q < 4; q++) {
                        const int ob = wid * 64 + of * 32 + kg * 4 + 8 * q;
                        float4 b4 = *(const float4*)(bias + ob);
                        half4 hv;
                        hv[0] = (_Float16)fmaxf(acc[of][pf][q * 4 + 0] + b4.x, 0.f);
                        hv[1] = (_Float16)fmaxf(acc[of][pf][q * 4 + 1] + b4.y, 0.f);
                        hv[2] = (_Float16)fmaxf(acc[of][pf][q * 4 + 2] + b4.z, 0.f);
                        hv[3] = (_Float16)fmaxf(acc[of][pf][q * 4 + 3] + b4.w, 0.f);
                        *(half4*)(tl + pb + ob) = hv;
                    }
                }
            }
        }
    }
}

// Proj: each wave owns one 64-px tile. MFMA 48x256 x px, LDS bounce, epilogue.
__global__ __launch_bounds__(256, 2) void proj_all_kernel(
    ProjParams P,
    const _Float16* __restrict__ tbuf,
    const _Float16* __restrict__ pAh,
    const _Float16* __restrict__ pAl,
    const float* __restrict__ cls_b,
    const float* __restrict__ off_b,
    float* __restrict__ out)
{
    __shared__ __align__(16) float sOut[4][64 * 52];
    const int tid  = threadIdx.x;
    const int lane = tid & 63;
    const int wid  = tid >> 6;

    int tile = blockIdx.x * 4 + wid;
    const bool tvalid = tile < NTILE;
    if (!tvalid) tile = NTILE - 1;
    int l = 0;
    #pragma unroll
    for (int i = 0; i < 5; i++) if (tile >= P.tcum[i]) l = i + 1;
    const int tprev = l ? P.tcum[l - 1] : 0;
    const long hw = P.hws[l];
    const long npx2 = 2 * hw;
    const long px0 = (long)(tile - tprev) * 64;
    const _Float16* tl = tbuf + P.toff[l];

    const int m16 = lane & 15;
    const int kq  = lane >> 4;

    f32x4 acc[3][4] = {};
    #pragma unroll
    for (int ks = 0; ks < 8; ks++) {
        half8 Ah[3], Al[3];
        #pragma unroll
        for (int mt = 0; mt < 3; mt++) {
            const long ao = (long)((mt * 8 + ks) * 64 + lane) * 8;
            Ah[mt] = *(const half8*)(pAh + ao);
            Al[mt] = *(const half8*)(pAl + ao);
        }
        #pragma unroll
        for (int nf = 0; nf < 4; nf++) {
            long px2 = px0 + nf * 16 + m16;
            if (px2 >= npx2) px2 = npx2 - 1;
            half8 Bv = *(const half8*)(tl + px2 * 256 + ks * 32 + kq * 8);
            #pragma unroll
            for (int mt = 0; mt < 3; mt++) {
                acc[mt][nf] = __builtin_amdgcn_mfma_f32_16x16x32_f16(Ah[mt], Bv, acc[mt][nf], 0, 0, 0);
                acc[mt][nf] = __builtin_amdgcn_mfma_f32_16x16x32_f16(Al[mt], Bv, acc[mt][nf], 0, 0, 0);
            }
        }
    }

    // bounce: [px-in-tile][52] fp32, conflict-free stride
    float* so = sOut[wid];
    #pragma unroll
    for (int nf = 0; nf < 4; nf++)
        #pragma unroll
        for (int mt = 0; mt < 3; mt++)
            *(f32x4*)(so + (nf * 16 + m16) * 52 + mt * 16 + kq * 4) = acc[mt][nf];
    __syncthreads();

    float v[48];
    #pragma unroll
    for (int j = 0; j < 12; j++) {
        f32x4 t4 = *(const f32x4*)(so + lane * 52 + j * 4);
        v[j*4+0] = t4[0]; v[j*4+1] = t4[1]; v[j*4+2] = t4[2]; v[j*4+3] = t4[3];
    }

    long px2 = px0 + lane;
    const bool pvalid = tvalid && (px2 < npx2);
    if (px2 >= npx2) px2 = npx2 - 1;
    const int b = px2 >= hw;
    const long pix = px2 - (b ? hw : 0);

    const float* eb = P.eps[l] + (long)b * 20 * hw + pix;
    const float* gb = P.gum[l] + (long)b * 5 * hw + pix;

    float wlog[5];
    float m = -1e30f;
    #pragma unroll
    for (int k = 0; k < 5; k++) {
        float u = gb[(long)k * hw];
        float g = -logf(-logf(u + 1e-10f) + 1e-10f);
        wlog[k] = (g + v[42 + k] + off_b[40 + k]) * 10.0f;
        m = fmaxf(m, wlog[k]);
    }
    float s = 0.f, cw[5];
    #pragma unroll
    for (int k = 0; k < 5; k++) { cw[k] = expf(wlog[k] - m); s += cw[k]; }
    float inv = 1.0f / s;

    float bbox[4] = {0.f, 0.f, 0.f, 0.f};
    #pragma unroll
    for (int k = 0; k < 5; k++) {
        float cwk = cw[k] * inv;
        #pragma unroll
        for (int j = 0; j < 4; j++) {
            int kj = k * 4 + j;
            float mean = v[2 + kj]  + off_b[kj];
            float lstd = v[22 + kj] + off_b[20 + kj];
            float sv = fmaf(expf(lstd), eb[(long)kj * hw], mean);
            bbox[j] = fmaf(cwk, sv, bbox[j]);
        }
    }

    if (pvalid) {
        float* ob = out + (long)b * TOTAL_PER_B + P.loff[l];
        float2 c2; c2.x = v[0] + cls_b[0]; c2.y = v[1] + cls_b[1];
        *(float2*)(ob + pix * 2) = c2;
        float* o2 = ob + hw * 2 + pix * 4;
        float2 b01; b01.x = bbox[0]; b01.y = bbox[1];
        float2 b23; b23.x = bbox[2]; b23.y = bbox[3];
        *(float2*)o2 = b01;
        *(float2*)(o2 + 2) = b23;
    }
}

extern "C" void kernel_launch(void* const* d_in, const int* in_sizes, int n_in,
                              void* d_out, int out_size, void* d_ws, size_t ws_size,
                              hipStream_t stream)
{
    static const int LH[5] = {200, 100, 50, 25, 13};
    static const int LW[5] = {336, 168, 84, 42, 21};

    const float* conv_w = (const float*)d_in[15];
    const float* conv_b = (const float*)d_in[16];
    const float* cls_w  = (const float*)d_in[17];
    const float* cls_b  = (const float*)d_in[18];
    const float* off_w  = (const float*)d_in[19];
    const float* off_b  = (const float*)d_in[20];

    _Float16* wh  = (_Float16*)d_ws;
    _Float16* wl  = wh + WT_F;
    _Float16* pAh = wl + WT_F;
    _Float16* pAl = pAh + PA_F;
    _Float16* tbuf = pAl + PA_F;

    ConvParams cp;
    ProjParams pp;
    long toff = 0, loff = 0;
    int cum = 0, tcum = 0;
    for (int l = 0; l < 5; l++) {
        int H = LH[l], W = LW[l];
        long hw = (long)H * W;
        cp.feat[l] = (const float*)d_in[3 * l];
        pp.eps[l]  = (const float*)d_in[3 * l + 1];
        pp.gum[l]  = (const float*)d_in[3 * l + 2];
        cp.toff[l] = toff; pp.toff[l] = toff;
        cp.Hs[l] = H; cp.Ws[l] = W;
        pp.hws[l] = hw;
        int gx = (W + 15) / 16, gy = (H + 7) / 8;
        cp.gxs[l] = gx;
        cum += gx * gy;
        cp.cum[l] = cum;
        pp.loff[l] = loff;
        tcum += (int)((2 * hw + 63) / 64);
        pp.tcum[l] = tcum;
        toff += 2L * hw * 256;
        loff += 6L * hw;
    }

    prep_kernel<<<32, 256, 0, stream>>>(conv_w, cls_w, off_w, wh, wl, pAh, pAl);

    conv_all_kernel<<<dim3((unsigned)cum, 1, 2), 256, 0, stream>>>(
        cp, wh, wl, conv_b, tbuf);

    proj_all_kernel<<<dim3((unsigned)((NTILE + 3) / 4)), 256, 0, stream>>>(
        pp, tbuf, pAh, pAl, cls_b, off_b, (float*)d_out);
}